// Round 1
// baseline (417.680 us; speedup 1.0000x reference)
//
#include <hip/hip_runtime.h>
#include <math.h>

// Problem: x[32, 2048, 1024] fp32; out[b, l, 0:1024] = x[b, l, :],
//          out[b, l, 1024] = sin(l / 2048).
// Flat-output-major vectorization: out has 67,174,400 floats (divisible by 4),
// each thread produces one aligned float4 of output. Row stride is 1025 floats
// (4100 B) so per-row float4 stores would be misaligned -- flat indexing keeps
// every store 16B-aligned. Source gathers are scalar but wave-coalesced.

__global__ __launch_bounds__(256) void pe_concat_kernel(
    const float* __restrict__ x, float* __restrict__ out, unsigned int n4) {
  unsigned int o4 = blockIdx.x * 256u + threadIdx.x;
  if (o4 >= n4) return;
  unsigned int o = o4 * 4u;

  // row in [0, 32*2048), col in [0, 1025)
  unsigned int row = o / 1025u;              // compiler emits magic-mul
  unsigned int col = o - row * 1025u;

  float v[4];
#pragma unroll
  for (int j = 0; j < 4; ++j) {
    float val;
    if (col < 1024u) {
      val = x[row * 1024u + col];
    } else {
      // l = row % 2048 (2048 rows per batch); pe = sin(l / 2048)
      float l = (float)(row & 2047u);
      val = sinf(l * (1.0f / 2048.0f));
    }
    ++col;
    if (col == 1025u) { col = 0u; ++row; }
    v[j] = val;
  }

  float4 r = make_float4(v[0], v[1], v[2], v[3]);
  reinterpret_cast<float4*>(out)[o4] = r;
}

extern "C" void kernel_launch(void* const* d_in, const int* in_sizes, int n_in,
                              void* d_out, int out_size, void* d_ws, size_t ws_size,
                              hipStream_t stream) {
  const float* x = (const float*)d_in[0];
  float* out = (float*)d_out;

  unsigned int n4 = (unsigned int)(out_size / 4);  // 16,793,600
  unsigned int grid = (n4 + 255u) / 256u;          // 65,600 blocks
  pe_concat_kernel<<<grid, 256, 0, stream>>>(x, out, n4);
}